// Round 3
// baseline (448.899 us; speedup 1.0000x reference)
//
#include <hip/hip_runtime.h>
#include <math.h>

#define NN 4096            // H*W
#define BN 32768           // B*H*W
#define CSTR 66            // Cs leading-dim pad (96 rows x 64 cols)

using short8 = __attribute__((ext_vector_type(8))) short;
using f32x4  = __attribute__((ext_vector_type(4))) float;
typedef unsigned short ushort_t;

__device__ inline unsigned f2bfu(float f) {
    unsigned u = __builtin_bit_cast(unsigned, f);
    u += 0x7FFFu + ((u >> 16) & 1u);        // RNE
    return u >> 16;
}
__device__ inline ushort_t f2bf(float f) { return (ushort_t)f2bfu(f); }
__device__ inline unsigned pack2(float a, float b) { return f2bfu(a) | (f2bfu(b) << 16); }
__device__ inline float bflo(unsigned u) { return __builtin_bit_cast(float, u << 16); }
__device__ inline float bfhi(unsigned u) { return __builtin_bit_cast(float, u & 0xFFFF0000u); }

// exact-GELU via Abramowitz-Stegun 7.1.26 erf (|err|<=1.5e-7, far below bf16 quant)
__device__ inline float gelu_f(float v) {
    float xx = v * 0.70710678118654752f;
    float a  = fabsf(xx);
    float t  = 1.0f / (1.0f + 0.3275911f * a);
    float p  = t*(0.254829592f + t*(-0.284496736f + t*(1.421413741f + t*(-1.453152027f + t*1.061405429f))));
    float erfv = 1.0f - p * __expf(-xx*xx);
    erfv = copysignf(erfv, xx);
    return 0.5f * v * (1.0f + erfv);
}

// 16-bf16 dot against q[16] from a position-major row chunk (2x dwordx4)
__device__ inline float dotk16(const unsigned* kv, const float* q) {
    const uint4 a = *(const uint4*)kv;
    const uint4 b = *(const uint4*)(kv + 4);
    float l;
    l  = q[0]*bflo(a.x)  + q[1]*bfhi(a.x);
    l += q[2]*bflo(a.y)  + q[3]*bfhi(a.y);
    l += q[4]*bflo(a.z)  + q[5]*bfhi(a.z);
    l += q[6]*bflo(a.w)  + q[7]*bfhi(a.w);
    l += q[8]*bflo(b.x)  + q[9]*bfhi(b.x);
    l += q[10]*bflo(b.y) + q[11]*bfhi(b.y);
    l += q[12]*bflo(b.z) + q[13]*bfhi(b.z);
    l += q[14]*bflo(b.w) + q[15]*bfhi(b.w);
    return l;
}
__device__ inline void accv16(const unsigned* kv, float wgt, float* o) {
    const uint4 a = *(const uint4*)kv;
    const uint4 b = *(const uint4*)(kv + 4);
    o[0]  += wgt*bflo(a.x);  o[1]  += wgt*bfhi(a.x);
    o[2]  += wgt*bflo(a.y);  o[3]  += wgt*bfhi(a.y);
    o[4]  += wgt*bflo(a.z);  o[5]  += wgt*bfhi(a.z);
    o[6]  += wgt*bflo(a.w);  o[7]  += wgt*bfhi(a.w);
    o[8]  += wgt*bflo(b.x);  o[9]  += wgt*bfhi(b.x);
    o[10] += wgt*bflo(b.y);  o[11] += wgt*bfhi(b.y);
    o[12] += wgt*bflo(b.z);  o[13] += wgt*bfhi(b.z);
    o[14] += wgt*bflo(b.w);  o[15] += wgt*bfhi(b.w);
}

// 64x96 @ 96x96 GEMM, A from LDS (stride 104 shorts), B directly from global
// prepacked weight image (L2-resident; dword layout row*52 + kc*16 + qd*4).
__device__ inline void gemm6_g(f32x4* acc, const ushort_t* A, const unsigned* wst,
                               int wv, int ln, int qd) {
    #pragma unroll
    for (int kc = 0; kc < 3; ++kc) {
        short8 a_ = *(const short8*)&A[(wv*16 + ln)*104 + kc*32 + qd*8];
        #pragma unroll
        for (int t = 0; t < 6; ++t) {
            uint4 br = *(const uint4*)&wst[(t*16 + ln)*52 + kc*16 + qd*4];
            short8 b_ = __builtin_bit_cast(short8, br);
            acc[t] = __builtin_amdgcn_mfma_f32_16x16x32_bf16(a_, b_, acc[t], 0, 0, 0);
        }
    }
}

// ============ K0: prepack all weight tiles to bf16 images ============
// stages: 0=Wq 1=Wk 2=Wv 3=Wproj 4/6/8/10=W1_kb 5/7/9/11=W2_kb
// layout: wbf dword d = stage*5120 + o*52 + qp  (row o: 48 data dwords + 4 pad)
__global__ __launch_bounds__(256) void k0_pack(
    const float* __restrict__ Wqkv, const float* __restrict__ Wproj,
    const float* __restrict__ W1, const float* __restrict__ W2,
    unsigned* __restrict__ wbf)
{
    int d = blockIdx.x * 256 + threadIdx.x;       // < 61440
    int s = d / 5120, r = d - s * 5120;
    int o = r / 52, qp = r - o * 52;
    unsigned val = 0u;
    if (o < 96 && qp < 48) {
        int q = qp * 2;
        float2 w2;
        if (s == 0)      w2 = *(const float2*)&Wqkv[(long)o * 96 + q];
        else if (s == 1) w2 = *(const float2*)&Wqkv[(long)(96 + o) * 96 + q];
        else if (s == 2) w2 = *(const float2*)&Wqkv[(long)(192 + o) * 96 + q];
        else if (s == 3) w2 = *(const float2*)&Wproj[(long)o * 96 + q];
        else if (((s - 4) & 1) == 0) { int kb = (s - 4) >> 1; w2 = *(const float2*)&W1[(long)(kb * 96 + o) * 96 + q]; }
        else                         { int kb = (s - 4) >> 1; w2 = *(const float2*)&W2[(long)o * 384 + kb * 96 + q]; }
        val = pack2(w2.x, w2.y);
    }
    wbf[d] = val;
}

// ============ K1: LN1 + Q/K/V GEMMs ============
// outputs: qimg = per-block 64x52-dword As-image of Q (bf16 pairs, pad zeroed)
//          kvt  = position-major rows: 96 dwords/pos = K(48) | V(48) bf16 pairs
__global__ __launch_bounds__(256, 3) void k1_ln_qkv(
    const float* __restrict__ x, const float* __restrict__ g1, const float* __restrict__ b1,
    const float* __restrict__ bqkv, const unsigned* __restrict__ wbf,
    unsigned* __restrict__ kvt32, unsigned* __restrict__ qimg)
{
    __shared__ __align__(16) float    Cs[96 * CSTR];
    __shared__ __align__(16) ushort_t As[64 * 104];
    __shared__ float lnm[64], lnr[64];
    const int tid = threadIdx.x;
    const int bid = blockIdx.x;
    const int wg  = ((bid & 7) << 6) | (bid >> 3);   // XCD-chunked: image b == XCD
    const long bn0 = (long)wg << 6;
    const int b  = (int)(bn0 >> 12);
    const int n0 = (int)(bn0 & 4095);
    const int lane = tid & 63, wv = tid >> 6;
    const int ln = lane & 15, qd = lane >> 4;

    for (int i = 0; i < 6; ++i) {
        int idx = i * 256 + tid;             // 1536 float4
        int c = idx >> 4, p4 = idx & 15;
        float4 v = *(const float4*)&x[((long)(b * 96 + c) << 12) + n0 + p4 * 4];
        float* dst = &Cs[c * CSTR + p4 * 4];
        dst[0] = v.x; dst[1] = v.y; dst[2] = v.z; dst[3] = v.w;
    }
    __syncthreads();                                   // S1: x ready
    {
        int p = tid >> 2, part = tid & 3, c0 = part * 24;
        float s = 0.f, ss = 0.f;
        for (int c = c0; c < c0 + 24; ++c) { float v = Cs[c*CSTR + p]; s += v; ss += v*v; }
        s  += __shfl_xor(s, 1);  s  += __shfl_xor(s, 2);
        ss += __shfl_xor(ss, 1); ss += __shfl_xor(ss, 2);
        float m = s * (1.f/96.f);
        float rstd = rsqrtf(ss * (1.f/96.f) - m*m + 1e-5f);
        if (part == 0) { lnm[p] = m; lnr[p] = rstd; }
    }
    __syncthreads();                                   // S2
    for (int i = 0; i < 12; ++i) {
        int idx = i * 256 + tid;
        int p = idx / 48, cp = idx % 48;
        float m = lnm[p], rs = lnr[p];
        int c = 2 * cp;
        *(unsigned*)&As[p * 104 + 2*cp] =
            pack2((Cs[c*CSTR + p]     - m) * rs * g1[c]   + b1[c],
                  (Cs[(c+1)*CSTR + p] - m) * rs * g1[c+1] + b1[c+1]);
    }
    __syncthreads();                                   // S3: As = LN1
    // ---- Q GEMM ----
    f32x4 acc[6];
    #pragma unroll
    for (int t = 0; t < 6; ++t) acc[t] = (f32x4){0.f,0.f,0.f,0.f};
    gemm6_g(acc, As, wbf, wv, ln, qd);                 // stage 0 = Wq
    #pragma unroll
    for (int t = 0; t < 6; ++t)
        #pragma unroll
        for (int r = 0; r < 4; ++r)
            Cs[(t*16 + ln)*CSTR + (wv*16 + qd*4 + r)] = acc[t][r];
    __syncthreads();                                   // S4: Cs = Q
    // ---- pack Q -> qimg; K GEMM (regs) overlaps ----
    for (int i = 0; i < 13; ++i) {
        int idx = i * 256 + tid;                       // 3328 dwords
        int p = idx / 52, cp = idx - p * 52;
        unsigned val = 0u;
        if (cp < 48) {
            int c = 2 * cp;
            val = pack2(Cs[c*CSTR + p] + bqkv[c], Cs[(c+1)*CSTR + p] + bqkv[c+1]);
        }
        qimg[(long)wg * 3328 + idx] = val;
    }
    #pragma unroll
    for (int t = 0; t < 6; ++t) acc[t] = (f32x4){0.f,0.f,0.f,0.f};
    gemm6_g(acc, As, wbf + 5120, wv, ln, qd);          // stage 1 = Wk
    __syncthreads();                                   // S5: Q-pack reads of Cs done
    #pragma unroll
    for (int t = 0; t < 6; ++t)
        #pragma unroll
        for (int r = 0; r < 4; ++r)
            Cs[(t*16 + ln)*CSTR + (wv*16 + qd*4 + r)] = acc[t][r];
    __syncthreads();                                   // S6: Cs = K
    // ---- pack K -> kvt rows; V GEMM overlaps ----
    for (int i = 0; i < 12; ++i) {
        int idx = i * 256 + tid;
        int p = idx / 48, cp = idx % 48;
        int c = 2 * cp;
        kvt32[(bn0 + p) * 96 + cp] =
            pack2(Cs[c*CSTR + p] + bqkv[96 + c], Cs[(c+1)*CSTR + p] + bqkv[96 + c + 1]);
    }
    #pragma unroll
    for (int t = 0; t < 6; ++t) acc[t] = (f32x4){0.f,0.f,0.f,0.f};
    gemm6_g(acc, As, wbf + 2*5120, wv, ln, qd);        // stage 2 = Wv
    __syncthreads();                                   // S7: K-pack reads of Cs done
    #pragma unroll
    for (int t = 0; t < 6; ++t)
        #pragma unroll
        for (int r = 0; r < 4; ++r)
            Cs[(t*16 + ln)*CSTR + (wv*16 + qd*4 + r)] = acc[t][r];
    __syncthreads();                                   // S8: Cs = V
    for (int i = 0; i < 12; ++i) {
        int idx = i * 256 + tid;
        int p = idx / 48, cp = idx % 48;
        int c = 2 * cp;
        kvt32[(bn0 + p) * 96 + 48 + cp] =
            pack2(Cs[c*CSTR + p] + bqkv[192 + c], Cs[(c+1)*CSTR + p] + bqkv[192 + c + 1]);
    }
}

// ============ K2345: attention + proj + LN2 + MLP + ReLU + L2norm ============
__global__ __launch_bounds__(256, 3) void k2345(
    const unsigned* __restrict__ kvt32, const unsigned* __restrict__ qimg,
    const float* __restrict__ x, const unsigned* __restrict__ wbf,
    const float* __restrict__ bproj,
    const float* __restrict__ g2, const float* __restrict__ b2,
    const float* __restrict__ bm1, const float* __restrict__ bm2,
    float* __restrict__ xcn)
{
    __shared__ __align__(16) float    Cs[96 * CSTR];   // x / xh'; bytes reused as Hs0 in MLP
    __shared__ __align__(16) ushort_t As[64 * 104];    // Q (async-staged) -> attn-out -> z
    __shared__ __align__(16) ushort_t Hs1[64 * 104];   // MLP hidden double-buffer (odd kb)
    __shared__ float lnm[64], lnr[64];
    ushort_t* Hs0 = (ushort_t*)Cs;                     // even kb (Cs dead during MLP)
    const int tid = threadIdx.x;
    const int bid = blockIdx.x;
    const int wg  = ((bid & 7) << 6) | (bid >> 3);     // XCD-chunked swizzle
    const long bn0 = (long)wg << 6;
    const int b  = (int)(bn0 >> 12);
    const int n0 = (int)(bn0 & 4095);
    const int h0 = n0 >> 6;
    const int lane = tid & 63, wv = tid >> 6;
    const int ln = lane & 15, qd = lane >> 4;

    {   // async Q image -> As (13 x 1024 B linear chunks)
        const unsigned* src = qimg + (long)wg * 3328 + lane * 4;
        #pragma unroll
        for (int i = 0; i < 4; ++i) {
            int chunk = wv + 4 * i;                    // wave-uniform
            if (chunk < 13)
                __builtin_amdgcn_global_load_lds(
                    (const __attribute__((address_space(1))) unsigned*)(src + chunk * 256),
                    (__attribute__((address_space(3))) unsigned*)((ushort_t*)As + chunk * 512),
                    16, 0, 0);
        }
    }
    for (int i = 0; i < 6; ++i) {
        int idx = i * 256 + tid;                       // 1536 float4
        int c = idx >> 4, p4 = idx & 15;
        float4 v = *(const float4*)&x[((long)(b * 96 + c) << 12) + n0 + p4 * 4];
        float* dst = &Cs[c * CSTR + p4 * 4];
        dst[0] = v.x; dst[1] = v.y; dst[2] = v.z; dst[3] = v.w;
    }
    __syncthreads();                                   // S1: As=Q, Cs=x
    // ---- attention: q from As, K/V position-major dwordx4; out in-place into As ----
    const unsigned* KV = kvt32 + (long)b * 4096 * 96;
    for (int it = 0; it < 2; ++it) {
        int item = it * 256 + tid;                     // 64 pos x 6 (dil,head)
        if (item < 384) {
            int p = item & 63;
            int r = item >> 6;
            int head = r & 1, di = r >> 1;
            int dil = di + 1;
            int cp0 = di*16 + head*8;                  // dword-channel offset
            int w = p;

            float q[16];
            #pragma unroll
            for (int j = 0; j < 8; ++j) {
                unsigned u = *(const unsigned*)&As[p * 104 + 2*(cp0 + j)];
                q[2*j] = bflo(u); q[2*j+1] = bfhi(u);
            }
            float logits[9];
            #pragma unroll
            for (int ki = 0; ki < 3; ++ki)
                #pragma unroll
                for (int kj = 0; kj < 3; ++kj) {
                    int hh = h0 + (ki-1)*dil, ww = w + (kj-1)*dil;
                    float l = 0.f;
                    if ((unsigned)hh < 64u && (unsigned)ww < 64u) {
                        int nn = (hh << 6) + ww;
                        l = dotk16(KV + (long)nn * 96 + cp0, q);
                    }
                    logits[ki*3 + kj] = l * 0.25f;
                }
            float m = logits[0];
            #pragma unroll
            for (int k = 1; k < 9; ++k) m = fmaxf(m, logits[k]);
            float e[9], s = 0.f;
            #pragma unroll
            for (int k = 0; k < 9; ++k) { e[k] = __expf(logits[k] - m); s += e[k]; }
            float inv = 1.f / s;
            float o[16];
            #pragma unroll
            for (int d = 0; d < 16; ++d) o[d] = 0.f;
            #pragma unroll
            for (int ki = 0; ki < 3; ++ki)
                #pragma unroll
                for (int kj = 0; kj < 3; ++kj) {
                    int hh = h0 + (ki-1)*dil, ww = w + (kj-1)*dil;
                    if ((unsigned)hh < 64u && (unsigned)ww < 64u) {
                        int nn = (hh << 6) + ww;
                        accv16(KV + (long)nn * 96 + 48 + cp0, e[ki*3 + kj] * inv, o);
                    }
                }
            #pragma unroll
            for (int j = 0; j < 8; ++j)
                *(unsigned*)&As[p * 104 + 2*(cp0 + j)] = pack2(o[2*j], o[2*j+1]);
        }
    }
    __syncthreads();                                   // S2: As = attn out
    // ---- proj GEMM; residual in regs (x from Cs) ----
    float resid[24];
    {
        f32x4 acc[6];
        #pragma unroll
        for (int t = 0; t < 6; ++t) acc[t] = (f32x4){0.f,0.f,0.f,0.f};
        gemm6_g(acc, As, wbf + 3*5120, wv, ln, qd);    // stage 3 = Wproj
        #pragma unroll
        for (int t = 0; t < 6; ++t) {
            int oc = t*16 + ln;
            float bias = bproj[oc];
            #pragma unroll
            for (int r = 0; r < 4; ++r) {
                int p = wv*16 + qd*4 + r;
                float v = acc[t][r] + bias + Cs[oc*CSTR + p];
                resid[t*4 + r] = v;
                Cs[oc*CSTR + p] = v;
            }
        }
    }
    __syncthreads();                                   // S3: Cs = xh'
    {
        int p = tid >> 2, part = tid & 3, c0 = part * 24;
        float s = 0.f, ss = 0.f;
        for (int c = c0; c < c0 + 24; ++c) { float v = Cs[c*CSTR + p]; s += v; ss += v*v; }
        s  += __shfl_xor(s, 1);  s  += __shfl_xor(s, 2);
        ss += __shfl_xor(ss, 1); ss += __shfl_xor(ss, 2);
        float m = s * (1.f/96.f);
        float rstd = rsqrtf(ss * (1.f/96.f) - m*m + 1e-5f);
        if (part == 0) { lnm[p] = m; lnr[p] = rstd; }
    }
    __syncthreads();                                   // S4
    for (int i = 0; i < 12; ++i) {
        int idx = i * 256 + tid;
        int p = idx / 48, cp = idx % 48;
        float m = lnm[p], rs = lnr[p];
        int c = 2 * cp;
        *(unsigned*)&As[p * 104 + 2*cp] =
            pack2((Cs[c*CSTR + p]     - m) * rs * g2[c]   + b2[c],
                  (Cs[(c+1)*CSTR + p] - m) * rs * g2[c+1] + b2[c+1]);
    }
    __syncthreads();                                   // S5: As = z (Cs now dead -> Hs0)
    // ---- MLP: H double-buffered, 1 barrier per kb ----
    f32x4 acc2[6];
    #pragma unroll
    for (int t = 0; t < 6; ++t) acc2[t] = (f32x4){0.f,0.f,0.f,0.f};
    #pragma unroll 1
    for (int kb = 0; kb < 4; ++kb) {
        ushort_t* H = (kb & 1) ? Hs1 : Hs0;
        f32x4 acch[6];
        #pragma unroll
        for (int t = 0; t < 6; ++t) acch[t] = (f32x4){0.f,0.f,0.f,0.f};
        gemm6_g(acch, As, wbf + (4 + 2*kb)*5120, wv, ln, qd);   // W1_kb
        #pragma unroll
        for (int t = 0; t < 6; ++t) {
            float bias = bm1[kb*96 + t*16 + ln];
            #pragma unroll
            for (int r = 0; r < 4; ++r)
                H[(wv*16 + qd*4 + r)*104 + t*16 + ln] = f2bf(gelu_f(acch[t][r] + bias));
        }
        __syncthreads();                               // B(kb): H ready; prev H reads done
        gemm6_g(acc2, H, wbf + (5 + 2*kb)*5120, wv, ln, qd);    // W2_kb
    }
    // last Hs0 read was GEMM2(kb=2), before B(3) -> safe to overwrite Cs now
    // ---- final residual + relu -> Cs ----
    #pragma unroll
    for (int t = 0; t < 6; ++t) {
        int oc = t*16 + ln;
        float bias = bm2[oc];
        #pragma unroll
        for (int r = 0; r < 4; ++r) {
            int p = wv*16 + qd*4 + r;
            float v = acc2[t][r] + bias + resid[t*4 + r];
            Cs[oc*CSTR + p] = fmaxf(v, 0.f);
        }
    }
    __syncthreads();                                   // S9
    {
        int p = tid >> 2, part = tid & 3, c0 = part * 24;
        float ss = 0.f;
        for (int c = c0; c < c0 + 24; ++c) { float v = Cs[c*CSTR + p]; ss += v*v; }
        ss += __shfl_xor(ss, 1); ss += __shfl_xor(ss, 2);
        if (part == 0) lnr[p] = 1.f / fmaxf(sqrtf(ss), 1e-12f);
    }
    __syncthreads();                                   // S10
    for (int i = 0; i < 12; ++i) {
        int idx = i * 256 + tid;
        int p = idx / 48, cp = idx % 48;
        float inv = lnr[p];
        float2 v = make_float2(Cs[(2*cp)*CSTR + p] * inv, Cs[(2*cp+1)*CSTR + p] * inv);
        *(float2*)&xcn[(bn0 + p) * 96 + 2*cp] = v;
    }
}

// ============ K6: 5x5 self-correlation (nontemporal native-vector stores) ============
__global__ __launch_bounds__(256) void k6_selfcorr(
    const float* __restrict__ xcn, float* __restrict__ out)
{
    __shared__ float xt[5 * 20 * 97];
    const int tid = threadIdx.x;
    const int wc = blockIdx.x;
    const int h  = blockIdx.y;
    const int b  = blockIdx.z;
    const int w0 = wc * 16;

    for (int i = 0; i < 38; ++i) {
        int idx = i * 256 + tid;
        if (idx < 9600) {
            int r = idx / (20 * 96);
            int rem = idx - r * (20 * 96);
            int wi = rem / 96, c = rem - wi * 96;
            int hh = h + r - 2, ww = w0 + wi - 2;
            float v = 0.f;
            if ((unsigned)hh < 64u && (unsigned)ww < 64u)
                v = xcn[(((long)b << 12) + (hh << 6) + ww) * 96 + c];
            xt[(r * 20 + wi) * 97 + c] = v;
        }
    }
    __syncthreads();
    f32x4* out4 = (f32x4*)out;
    const long ob4 = (long)b * 2457600 + (long)h * 400 + wc * 100;
    for (int i = 0; i < 38; ++i) {
        int idx = i * 256 + tid;             // 9600 float4 slots
        if (idx < 9600) {
            int c = idx / 100;
            int r4 = idx - c * 100;
            f32x4 v;
            #pragma unroll
            for (int j = 0; j < 4; ++j) {
                int r = r4 * 4 + j;
                int lw = r / 25, k = r - lw * 25;
                int ki = k / 5, kj = k - ki * 5;
                float center = xt[(42 + lw) * 97 + c];
                float neigh  = xt[(ki * 20 + lw + kj) * 97 + c];
                v[j] = center * neigh;
            }
            __builtin_nontemporal_store(v, &out4[ob4 + (long)c * 25600 + r4]);
        }
    }
}

// ============ launcher ============
extern "C" void kernel_launch(void* const* d_in, const int* in_sizes, int n_in,
                              void* d_out, int out_size, void* d_ws, size_t ws_size,
                              hipStream_t stream)
{
    const float* x     = (const float*)d_in[0];
    const float* g1    = (const float*)d_in[1];
    const float* b1    = (const float*)d_in[2];
    const float* Wqkv  = (const float*)d_in[3];
    const float* bqkv  = (const float*)d_in[4];
    const float* Wproj = (const float*)d_in[5];
    const float* bproj = (const float*)d_in[6];
    const float* g2    = (const float*)d_in[7];
    const float* b2    = (const float*)d_in[8];
    const float* W1    = (const float*)d_in[9];
    const float* bm1   = (const float*)d_in[10];
    const float* W2    = (const float*)d_in[11];
    const float* bm2   = (const float*)d_in[12];
    float* out = (float*)d_out;

    char* w = (char*)d_ws;
    unsigned* wbf   = (unsigned*)w;  w += 12 * 20480;             // prepacked bf16 weights
    unsigned* kvt32 = (unsigned*)w;  w += (size_t)BN * 96 * 4;    // K|V position-major rows
    unsigned* qimg  = (unsigned*)w;  w += (size_t)512 * 3328 * 4; // per-block Q As-images
    float*    xcn   = (float*)w;

    k0_pack    <<<240, 256, 0, stream>>>(Wqkv, Wproj, W1, W2, wbf);
    k1_ln_qkv  <<<BN / 64, 256, 0, stream>>>(x, g1, b1, bqkv, wbf, kvt32, qimg);
    k2345      <<<BN / 64, 256, 0, stream>>>(kvt32, qimg, x, wbf,
                                             bproj, g2, b2, bm1, bm2, xcn);
    k6_selfcorr<<<dim3(4, 64, 8), 256, 0, stream>>>(xcn, out);
}

// Round 4
// 415.151 us; speedup vs baseline: 1.0813x; 1.0813x over previous
//
#include <hip/hip_runtime.h>
#include <math.h>

#define NN 4096            // H*W
#define BN 32768           // B*H*W
#define CSTR 66            // Cs leading-dim pad (96 rows x 64 cols)

using short8 = __attribute__((ext_vector_type(8))) short;
using f32x4  = __attribute__((ext_vector_type(4))) float;
typedef unsigned short ushort_t;

__device__ inline unsigned f2bfu(float f) {
    unsigned u = __builtin_bit_cast(unsigned, f);
    u += 0x7FFFu + ((u >> 16) & 1u);        // RNE
    return u >> 16;
}
__device__ inline ushort_t f2bf(float f) { return (ushort_t)f2bfu(f); }
__device__ inline unsigned pack2(float a, float b) { return f2bfu(a) | (f2bfu(b) << 16); }
__device__ inline float bflo(unsigned u) { return __builtin_bit_cast(float, u << 16); }
__device__ inline float bfhi(unsigned u) { return __builtin_bit_cast(float, u & 0xFFFF0000u); }

// exact-GELU via Abramowitz-Stegun 7.1.26 erf (|err|<=1.5e-7, far below bf16 quant)
__device__ inline float gelu_f(float v) {
    float xx = v * 0.70710678118654752f;
    float a  = fabsf(xx);
    float t  = 1.0f / (1.0f + 0.3275911f * a);
    float p  = t*(0.254829592f + t*(-0.284496736f + t*(1.421413741f + t*(-1.453152027f + t*1.061405429f))));
    float erfv = 1.0f - p * __expf(-xx*xx);
    erfv = copysignf(erfv, xx);
    return 0.5f * v * (1.0f + erfv);
}

// async global->LDS copy of one prepacked 96x104-bf16 weight stage (20480 B, linear)
__device__ inline void stage_w(const unsigned* __restrict__ wbf, int stage,
                               ushort_t* dst, int wv, int lane) {
    const unsigned* src = wbf + (long)stage * 5120 + lane * 4;
    #pragma unroll
    for (int i = 0; i < 5; ++i) {
        int chunk = wv + 4 * i;               // 20 chunks x 1024 B, wave-uniform LDS base
        __builtin_amdgcn_global_load_lds(
            (const __attribute__((address_space(1))) unsigned*)(src + chunk * 256),
            (__attribute__((address_space(3))) unsigned*)(dst + chunk * 512),
            16, 0, 0);
    }
}

// 16-bf16 dot of q[16] against two register uint4s
__device__ inline float dotreg(const uint4& a, const uint4& b, const float* q) {
    float l;
    l  = q[0]*bflo(a.x)  + q[1]*bfhi(a.x);
    l += q[2]*bflo(a.y)  + q[3]*bfhi(a.y);
    l += q[4]*bflo(a.z)  + q[5]*bfhi(a.z);
    l += q[6]*bflo(a.w)  + q[7]*bfhi(a.w);
    l += q[8]*bflo(b.x)  + q[9]*bfhi(b.x);
    l += q[10]*bflo(b.y) + q[11]*bfhi(b.y);
    l += q[12]*bflo(b.z) + q[13]*bfhi(b.z);
    l += q[14]*bflo(b.w) + q[15]*bfhi(b.w);
    return l;
}
__device__ inline void accreg(const uint4& a, const uint4& b, float wgt, float* o) {
    o[0]  += wgt*bflo(a.x);  o[1]  += wgt*bfhi(a.x);
    o[2]  += wgt*bflo(a.y);  o[3]  += wgt*bfhi(a.y);
    o[4]  += wgt*bflo(a.z);  o[5]  += wgt*bfhi(a.z);
    o[6]  += wgt*bflo(a.w);  o[7]  += wgt*bfhi(a.w);
    o[8]  += wgt*bflo(b.x);  o[9]  += wgt*bfhi(b.x);
    o[10] += wgt*bflo(b.y);  o[11] += wgt*bfhi(b.y);
    o[12] += wgt*bflo(b.z);  o[13] += wgt*bfhi(b.z);
    o[14] += wgt*bflo(b.w);  o[15] += wgt*bfhi(b.w);
}

#define MFMA_GEMM6(ACC, APTR, BPTR)                                              \
    _Pragma("unroll")                                                            \
    for (int kc = 0; kc < 3; ++kc) {                                             \
        short8 a_ = *(const short8*)&(APTR)[(wv*16 + ln)*104 + kc*32 + qd*8];    \
        _Pragma("unroll")                                                        \
        for (int t = 0; t < 6; ++t) {                                            \
            short8 b_ = *(const short8*)&(BPTR)[(t*16 + ln)*104 + kc*32 + qd*8]; \
            ACC[t] = __builtin_amdgcn_mfma_f32_16x16x32_bf16(a_, b_, ACC[t], 0, 0, 0); \
        }                                                                        \
    }

// ============ K0: prepack all weight tiles to bf16 LDS images ============
// stages: 0=Wq 1=Wk 2=Wv 3=Wproj 4/6/8/10=W1_kb 5/7/9/11=W2_kb
// layout: wbf dword d = stage*5120 + o*52 + qp  (row o: 48 data dwords + 4 pad)
__global__ __launch_bounds__(256) void k0_pack(
    const float* __restrict__ Wqkv, const float* __restrict__ Wproj,
    const float* __restrict__ W1, const float* __restrict__ W2,
    unsigned* __restrict__ wbf)
{
    int d = blockIdx.x * 256 + threadIdx.x;       // < 61440
    int s = d / 5120, r = d - s * 5120;
    int o = r / 52, qp = r - o * 52;
    unsigned val = 0u;
    if (o < 96 && qp < 48) {
        int q = qp * 2;
        float2 w2;
        if (s == 0)      w2 = *(const float2*)&Wqkv[(long)o * 96 + q];
        else if (s == 1) w2 = *(const float2*)&Wqkv[(long)(96 + o) * 96 + q];
        else if (s == 2) w2 = *(const float2*)&Wqkv[(long)(192 + o) * 96 + q];
        else if (s == 3) w2 = *(const float2*)&Wproj[(long)o * 96 + q];
        else if (((s - 4) & 1) == 0) { int kb = (s - 4) >> 1; w2 = *(const float2*)&W1[(long)(kb * 96 + o) * 96 + q]; }
        else                         { int kb = (s - 4) >> 1; w2 = *(const float2*)&W2[(long)o * 384 + kb * 96 + q]; }
        val = pack2(w2.x, w2.y);
    }
    wbf[d] = val;
}

// ============ K1: LN1 + K/V GEMMs -> kvt position-major rows ============
// kvt row layout: pos*96 dwords = K(48 bf16-pairs) | V(48 bf16-pairs)
__global__ __launch_bounds__(256, 2) void k1_ln_kv(
    const float* __restrict__ x, const float* __restrict__ g1, const float* __restrict__ b1,
    const float* __restrict__ bqkv, const unsigned* __restrict__ wbf,
    unsigned* __restrict__ kvt32)
{
    __shared__ __align__(16) float    Cs[96 * CSTR];
    __shared__ __align__(16) ushort_t As[64 * 104];
    __shared__ __align__(16) ushort_t Bs[2][10240];
    __shared__ float lnm[64], lnr[64];
    const int tid = threadIdx.x;
    const int bid = blockIdx.x;
    const int wg  = ((bid & 7) << 6) | (bid >> 3);   // XCD-chunked: image b == XCD
    const long bn0 = (long)wg << 6;
    const int b  = (int)(bn0 >> 12);
    const int n0 = (int)(bn0 & 4095);
    const int lane = tid & 63, wv = tid >> 6;
    const int ln = lane & 15, qd = lane >> 4;

    stage_w(wbf, 1, &Bs[0][0], wv, lane);    // Wk
    stage_w(wbf, 2, &Bs[1][0], wv, lane);    // Wv
    for (int i = 0; i < 6; ++i) {
        int idx = i * 256 + tid;             // 1536 float4
        int c = idx >> 4, p4 = idx & 15;
        float4 v = *(const float4*)&x[((long)(b * 96 + c) << 12) + n0 + p4 * 4];
        float* dst = &Cs[c * CSTR + p4 * 4];
        dst[0] = v.x; dst[1] = v.y; dst[2] = v.z; dst[3] = v.w;
    }
    __syncthreads();                                   // S1: x, Wk, Wv ready
    {
        int p = tid >> 2, part = tid & 3, c0 = part * 24;
        float s = 0.f, ss = 0.f;
        for (int c = c0; c < c0 + 24; ++c) { float v = Cs[c*CSTR + p]; s += v; ss += v*v; }
        s  += __shfl_xor(s, 1);  s  += __shfl_xor(s, 2);
        ss += __shfl_xor(ss, 1); ss += __shfl_xor(ss, 2);
        float m = s * (1.f/96.f);
        float rstd = rsqrtf(ss * (1.f/96.f) - m*m + 1e-5f);
        if (part == 0) { lnm[p] = m; lnr[p] = rstd; }
    }
    __syncthreads();                                   // S2
    for (int i = 0; i < 12; ++i) {
        int idx = i * 256 + tid;
        int p = idx / 48, cp = idx % 48;
        float m = lnm[p], rs = lnr[p];
        int c = 2 * cp;
        *(unsigned*)&As[p * 104 + 2*cp] =
            pack2((Cs[c*CSTR + p]     - m) * rs * g1[c]   + b1[c],
                  (Cs[(c+1)*CSTR + p] - m) * rs * g1[c+1] + b1[c+1]);
    }
    __syncthreads();                                   // S3: As = LN1
    // ---- K GEMM ----
    f32x4 acc[6];
    #pragma unroll
    for (int t = 0; t < 6; ++t) acc[t] = (f32x4){0.f,0.f,0.f,0.f};
    MFMA_GEMM6(acc, As, Bs[0]);
    #pragma unroll
    for (int t = 0; t < 6; ++t)
        #pragma unroll
        for (int r = 0; r < 4; ++r)
            Cs[(t*16 + ln)*CSTR + (wv*16 + qd*4 + r)] = acc[t][r];
    __syncthreads();                                   // S4: Cs = K
    // ---- V GEMM (regs) overlaps the K pack/store ----
    f32x4 accv[6];
    #pragma unroll
    for (int t = 0; t < 6; ++t) accv[t] = (f32x4){0.f,0.f,0.f,0.f};
    for (int i = 0; i < 12; ++i) {
        int idx = i * 256 + tid;
        int p = idx / 48, cp = idx % 48;
        int c = 2 * cp;
        kvt32[(bn0 + p) * 96 + cp] =
            pack2(Cs[c*CSTR + p] + bqkv[96 + c], Cs[(c+1)*CSTR + p] + bqkv[96 + c + 1]);
    }
    MFMA_GEMM6(accv, As, Bs[1]);
    __syncthreads();                                   // S5: K-pack reads of Cs done
    #pragma unroll
    for (int t = 0; t < 6; ++t)
        #pragma unroll
        for (int r = 0; r < 4; ++r)
            Cs[(t*16 + ln)*CSTR + (wv*16 + qd*4 + r)] = accv[t][r];
    __syncthreads();                                   // S6: Cs = V
    for (int i = 0; i < 12; ++i) {
        int idx = i * 256 + tid;
        int p = idx / 48, cp = idx % 48;
        int c = 2 * cp;
        kvt32[(bn0 + p) * 96 + 48 + cp] =
            pack2(Cs[c*CSTR + p] + bqkv[192 + c], Cs[(c+1)*CSTR + p] + bqkv[192 + c + 1]);
    }
}

// ============ K2345: Q-GEMM + attention + proj + LN2 + MLP + ReLU + L2norm ============
__global__ __launch_bounds__(256, 2) void k2345(
    const unsigned* __restrict__ kvt32, const float* __restrict__ x,
    const float* __restrict__ g1, const float* __restrict__ b1,
    const float* __restrict__ bqkv, const unsigned* __restrict__ wbf,
    const float* __restrict__ bproj,
    const float* __restrict__ g2, const float* __restrict__ b2,
    const float* __restrict__ bm1, const float* __restrict__ bm2,
    float* __restrict__ xcn)
{
    __shared__ __align__(16) float    Cs[96 * CSTR];   // x / xh'; bytes reused as Hs in MLP
    __shared__ __align__(16) ushort_t As[64 * 104];    // LN1 -> Q (in place) -> attn-out -> z
    __shared__ __align__(16) ushort_t Bs[2][10240];    // double-buffered weight stages
    __shared__ float lnm[64], lnr[64];
    ushort_t* Hs = (ushort_t*)Cs;                      // MLP hidden frags (Cs dead then)
    const int tid = threadIdx.x;
    const int bid = blockIdx.x;
    const int wg  = ((bid & 7) << 6) | (bid >> 3);     // XCD-chunked swizzle
    const long bn0 = (long)wg << 6;
    const int b  = (int)(bn0 >> 12);
    const int n0 = (int)(bn0 & 4095);
    const int h0 = n0 >> 6;
    const int lane = tid & 63, wv = tid >> 6;
    const int ln = lane & 15, qd = lane >> 4;

    stage_w(wbf, 0, &Bs[0][0], wv, lane);    // Wq
    stage_w(wbf, 3, &Bs[1][0], wv, lane);    // Wproj
    // ---- pre-barrier K-hoist for item = tid (r0 in 0..3): addresses are
    //      data-independent; 18 dwordx4 loads fly under x-stage + LN1 + Q GEMM ----
    const unsigned* KV = kvt32 + (long)b * 4096 * 96;
    const int p0 = tid & 63, r0 = tid >> 6;
    const int head0 = r0 & 1, di0 = r0 >> 1, dil0 = di0 + 1;
    const int cp00 = di0*16 + head0*8;
    uint4 kr[9][2];
    #pragma unroll
    for (int ki = 0; ki < 3; ++ki)
        #pragma unroll
        for (int kj = 0; kj < 3; ++kj) {
            int nidx = ki*3 + kj;
            int hh = h0 + (ki-1)*dil0, ww = p0 + (kj-1)*dil0;
            kr[nidx][0] = (uint4){0u,0u,0u,0u};
            kr[nidx][1] = (uint4){0u,0u,0u,0u};
            if ((unsigned)hh < 64u && (unsigned)ww < 64u) {
                const unsigned* src = KV + ((long)((hh << 6) + ww)) * 96 + cp00;
                kr[nidx][0] = *(const uint4*)src;
                kr[nidx][1] = *(const uint4*)(src + 4);
            }
        }
    for (int i = 0; i < 6; ++i) {
        int idx = i * 256 + tid;                       // 1536 float4
        int c = idx >> 4, p4 = idx & 15;
        float4 v = *(const float4*)&x[((long)(b * 96 + c) << 12) + n0 + p4 * 4];
        float* dst = &Cs[c * CSTR + p4 * 4];
        dst[0] = v.x; dst[1] = v.y; dst[2] = v.z; dst[3] = v.w;
    }
    __syncthreads();                                   // S1: x + Wq + Wproj ready
    {
        int p = tid >> 2, part = tid & 3, c0 = part * 24;
        float s = 0.f, ss = 0.f;
        for (int c = c0; c < c0 + 24; ++c) { float v = Cs[c*CSTR + p]; s += v; ss += v*v; }
        s  += __shfl_xor(s, 1);  s  += __shfl_xor(s, 2);
        ss += __shfl_xor(ss, 1); ss += __shfl_xor(ss, 2);
        float m = s * (1.f/96.f);
        float rstd = rsqrtf(ss * (1.f/96.f) - m*m + 1e-5f);
        if (part == 0) { lnm[p] = m; lnr[p] = rstd; }
    }
    __syncthreads();                                   // S2
    for (int i = 0; i < 12; ++i) {
        int idx = i * 256 + tid;
        int p = idx / 48, cp = idx % 48;
        float m = lnm[p], rs = lnr[p];
        int c = 2 * cp;
        *(unsigned*)&As[p * 104 + 2*cp] =
            pack2((Cs[c*CSTR + p]     - m) * rs * g1[c]   + b1[c],
                  (Cs[(c+1)*CSTR + p] - m) * rs * g1[c+1] + b1[c+1]);
    }
    __syncthreads();                                   // S3: As = LN1
    // ---- Q MFMA -> back into As (per-wave row-disjoint, in-wave RAW->WAR safe) ----
    {
        f32x4 acc[6];
        #pragma unroll
        for (int t = 0; t < 6; ++t) acc[t] = (f32x4){0.f,0.f,0.f,0.f};
        MFMA_GEMM6(acc, As, Bs[0]);
        #pragma unroll
        for (int t = 0; t < 6; ++t) {
            float bias = bqkv[t*16 + ln];
            #pragma unroll
            for (int r = 0; r < 4; ++r)
                As[(wv*16 + qd*4 + r)*104 + t*16 + ln] = f2bf(acc[t][r] + bias);
        }
    }
    __syncthreads();                                   // S4: As = Q
    stage_w(wbf, 4, &Bs[0][0], wv, lane);              // W1_0 under attention
    // ---- attention item 0 (all 256 threads): K from regs, V loads issued first ----
    {
        uint4 vr[9][2];
        #pragma unroll
        for (int ki = 0; ki < 3; ++ki)
            #pragma unroll
            for (int kj = 0; kj < 3; ++kj) {
                int nidx = ki*3 + kj;
                int hh = h0 + (ki-1)*dil0, ww = p0 + (kj-1)*dil0;
                vr[nidx][0] = (uint4){0u,0u,0u,0u};
                vr[nidx][1] = (uint4){0u,0u,0u,0u};
                if ((unsigned)hh < 64u && (unsigned)ww < 64u) {
                    const unsigned* src = KV + ((long)((hh << 6) + ww)) * 96 + 48 + cp00;
                    vr[nidx][0] = *(const uint4*)src;
                    vr[nidx][1] = *(const uint4*)(src + 4);
                }
            }
        float q[16];
        #pragma unroll
        for (int j = 0; j < 8; ++j) {
            unsigned u = *(const unsigned*)&As[p0 * 104 + 2*(cp00 + j)];
            q[2*j] = bflo(u); q[2*j+1] = bfhi(u);
        }
        float logits[9];
        #pragma unroll
        for (int k = 0; k < 9; ++k)
            logits[k] = dotreg(kr[k][0], kr[k][1], q) * 0.25f;   // OOB: zero K -> 0
        float m = logits[0];
        #pragma unroll
        for (int k = 1; k < 9; ++k) m = fmaxf(m, logits[k]);
        float e[9], s = 0.f;
        #pragma unroll
        for (int k = 0; k < 9; ++k) { e[k] = __expf(logits[k] - m); s += e[k]; }
        float inv = 1.f / s;
        float o[16];
        #pragma unroll
        for (int d = 0; d < 16; ++d) o[d] = 0.f;
        #pragma unroll
        for (int k = 0; k < 9; ++k)
            accreg(vr[k][0], vr[k][1], e[k] * inv, o);           // OOB: zero V -> +0
        #pragma unroll
        for (int j = 0; j < 8; ++j)
            *(unsigned*)&As[p0 * 104 + 2*(cp00 + j)] = pack2(o[2*j], o[2*j+1]);
    }
    // ---- attention item 1 (threads 0..127): items 256..383, inline loads ----
    if (tid < 128) {
        int item = 256 + tid;
        int p = item & 63;
        int r = item >> 6;                             // 4..5
        int head = r & 1, di = r >> 1;                 // di = 2
        int dil = di + 1;
        int cp0 = di*16 + head*8;
        float q[16];
        #pragma unroll
        for (int j = 0; j < 8; ++j) {
            unsigned u = *(const unsigned*)&As[p * 104 + 2*(cp0 + j)];
            q[2*j] = bflo(u); q[2*j+1] = bfhi(u);
        }
        float logits[9];
        #pragma unroll
        for (int ki = 0; ki < 3; ++ki)
            #pragma unroll
            for (int kj = 0; kj < 3; ++kj) {
                int hh = h0 + (ki-1)*dil, ww = p + (kj-1)*dil;
                float l = 0.f;
                if ((unsigned)hh < 64u && (unsigned)ww < 64u) {
                    const unsigned* src = KV + ((long)((hh << 6) + ww)) * 96 + cp0;
                    uint4 a = *(const uint4*)src, bb = *(const uint4*)(src + 4);
                    float qq[16];
                    #pragma unroll
                    for (int j = 0; j < 16; ++j) qq[j] = q[j];
                    l = dotreg(a, bb, qq);
                }
                logits[ki*3 + kj] = l * 0.25f;
            }
        float m = logits[0];
        #pragma unroll
        for (int k = 1; k < 9; ++k) m = fmaxf(m, logits[k]);
        float e[9], s = 0.f;
        #pragma unroll
        for (int k = 0; k < 9; ++k) { e[k] = __expf(logits[k] - m); s += e[k]; }
        float inv = 1.f / s;
        float o[16];
        #pragma unroll
        for (int d = 0; d < 16; ++d) o[d] = 0.f;
        #pragma unroll
        for (int ki = 0; ki < 3; ++ki)
            #pragma unroll
            for (int kj = 0; kj < 3; ++kj) {
                int hh = h0 + (ki-1)*dil, ww = p + (kj-1)*dil;
                if ((unsigned)hh < 64u && (unsigned)ww < 64u) {
                    const unsigned* src = KV + ((long)((hh << 6) + ww)) * 96 + 48 + cp0;
                    uint4 a = *(const uint4*)src, bb = *(const uint4*)(src + 4);
                    accreg(a, bb, e[ki*3 + kj] * inv, o);
                }
            }
        #pragma unroll
        for (int j = 0; j < 8; ++j)
            *(unsigned*)&As[p * 104 + 2*(cp0 + j)] = pack2(o[2*j], o[2*j+1]);
    }
    __syncthreads();                                   // S5: As = attn out; W1_0 landed
    // ---- proj MFMA; residual in regs (x read from Cs) ----
    float resid[24];
    {
        f32x4 acc[6];
        #pragma unroll
        for (int t = 0; t < 6; ++t) acc[t] = (f32x4){0.f,0.f,0.f,0.f};
        MFMA_GEMM6(acc, As, Bs[1]);
        #pragma unroll
        for (int t = 0; t < 6; ++t) {
            int oc = t*16 + ln;
            float bias = bproj[oc];
            #pragma unroll
            for (int r = 0; r < 4; ++r) {
                int p = wv*16 + qd*4 + r;
                float v = acc[t][r] + bias + Cs[oc*CSTR + p];
                resid[t*4 + r] = v;
                Cs[oc*CSTR + p] = v;
            }
        }
    }
    __syncthreads();                                   // S6: Cs = xh'
    stage_w(wbf, 5, &Bs[1][0], wv, lane);              // W2_0 under LN2
    {
        int p = tid >> 2, part = tid & 3, c0 = part * 24;
        float s = 0.f, ss = 0.f;
        for (int c = c0; c < c0 + 24; ++c) { float v = Cs[c*CSTR + p]; s += v; ss += v*v; }
        s  += __shfl_xor(s, 1);  s  += __shfl_xor(s, 2);
        ss += __shfl_xor(ss, 1); ss += __shfl_xor(ss, 2);
        float m = s * (1.f/96.f);
        float rstd = rsqrtf(ss * (1.f/96.f) - m*m + 1e-5f);
        if (part == 0) { lnm[p] = m; lnr[p] = rstd; }
    }
    __syncthreads();                                   // S7
    for (int i = 0; i < 12; ++i) {
        int idx = i * 256 + tid;
        int p = idx / 48, cp = idx % 48;
        float m = lnm[p], rs = lnr[p];
        int c = 2 * cp;
        *(unsigned*)&As[p * 104 + 2*cp] =
            pack2((Cs[c*CSTR + p]     - m) * rs * g2[c]   + b2[c],
                  (Cs[(c+1)*CSTR + p] - m) * rs * g2[c+1] + b2[c+1]);
    }
    __syncthreads();                                   // S8: As = z; Bs0=W1_0, Bs1=W2_0 ready
    // ---- MLP: W1_{kb+1} hides under GEMM2_kb, W2_{kb+1} under GEMM1_{kb+1} ----
    f32x4 acc2[6];
    #pragma unroll
    for (int t = 0; t < 6; ++t) acc2[t] = (f32x4){0.f,0.f,0.f,0.f};
    for (int kb = 0; kb < 4; ++kb) {
        f32x4 acch[6];
        #pragma unroll
        for (int t = 0; t < 6; ++t) acch[t] = (f32x4){0.f,0.f,0.f,0.f};
        MFMA_GEMM6(acch, As, Bs[0]);                   // GEMM1: W1_kb
        #pragma unroll
        for (int t = 0; t < 6; ++t) {
            float bias = bm1[kb*96 + t*16 + ln];
            #pragma unroll
            for (int r = 0; r < 4; ++r)
                Hs[(wv*16 + qd*4 + r)*104 + t*16 + ln] = f2bf(gelu_f(acch[t][r] + bias));
        }
        __syncthreads();                               // B1: Hs ready, Bs0 free
        if (kb < 3) stage_w(wbf, 6 + 2*kb, &Bs[0][0], wv, lane);   // W1_{kb+1}
        MFMA_GEMM6(acc2, Hs, Bs[1]);                   // GEMM2: W2_kb
        __syncthreads();                               // B2: Bs1 free; W1_{kb+1} landed
        if (kb < 3) stage_w(wbf, 7 + 2*kb, &Bs[1][0], wv, lane);   // W2_{kb+1}
    }
    // ---- final residual + relu -> Cs ----
    #pragma unroll
    for (int t = 0; t < 6; ++t) {
        int oc = t*16 + ln;
        float bias = bm2[oc];
        #pragma unroll
        for (int r = 0; r < 4; ++r) {
            int p = wv*16 + qd*4 + r;
            float v = acc2[t][r] + bias + resid[t*4 + r];
            Cs[oc*CSTR + p] = fmaxf(v, 0.f);
        }
    }
    __syncthreads();                                   // S9
    {
        int p = tid >> 2, part = tid & 3, c0 = part * 24;
        float ss = 0.f;
        for (int c = c0; c < c0 + 24; ++c) { float v = Cs[c*CSTR + p]; ss += v*v; }
        ss += __shfl_xor(ss, 1); ss += __shfl_xor(ss, 2);
        if (part == 0) lnr[p] = 1.f / fmaxf(sqrtf(ss), 1e-12f);
    }
    __syncthreads();                                   // S10
    for (int i = 0; i < 12; ++i) {
        int idx = i * 256 + tid;
        int p = idx / 48, cp = idx % 48;
        float inv = lnr[p];
        float2 v = make_float2(Cs[(2*cp)*CSTR + p] * inv, Cs[(2*cp+1)*CSTR + p] * inv);
        *(float2*)&xcn[(bn0 + p) * 96 + 2*cp] = v;
    }
}

// ============ K6: 5x5 self-correlation (vectorized halo stage, nontemporal stores) ============
__global__ __launch_bounds__(256) void k6_selfcorr(
    const float* __restrict__ xcn, float* __restrict__ out)
{
    __shared__ float xt[5 * 20 * 97];
    const int tid = threadIdx.x;
    const int wc = blockIdx.x;
    const int h  = blockIdx.y;
    const int b  = blockIdx.z;
    const int w0 = wc * 16;

    const f32x4* xcn4 = (const f32x4*)xcn;
    for (int i = 0; i < 10; ++i) {
        int idx = i * 256 + tid;                       // 2400 float4 slots
        if (idx < 2400) {
            int r = idx / 480;
            int rem = idx - r * 480;
            int wi = rem / 24, c4 = rem - wi * 24;
            int hh = h + r - 2, ww = w0 + wi - 2;
            f32x4 v = (f32x4){0.f, 0.f, 0.f, 0.f};
            if ((unsigned)hh < 64u && (unsigned)ww < 64u)
                v = xcn4[(((long)b << 12) + (hh << 6) + ww) * 24 + c4];
            float* dst = &xt[(r * 20 + wi) * 97 + c4 * 4];
            dst[0] = v[0]; dst[1] = v[1]; dst[2] = v[2]; dst[3] = v[3];
        }
    }
    __syncthreads();
    f32x4* out4 = (f32x4*)out;
    const long ob4 = (long)b * 2457600 + (long)h * 400 + wc * 100;
    for (int i = 0; i < 38; ++i) {
        int idx = i * 256 + tid;             // 9600 float4 slots
        if (idx < 9600) {
            int c = idx / 100;
            int r4 = idx - c * 100;
            f32x4 v;
            #pragma unroll
            for (int j = 0; j < 4; ++j) {
                int r = r4 * 4 + j;
                int lw = r / 25, k = r - lw * 25;
                int ki = k / 5, kj = k - ki * 5;
                float center = xt[(42 + lw) * 97 + c];
                float neigh  = xt[(ki * 20 + lw + kj) * 97 + c];
                v[j] = center * neigh;
            }
            __builtin_nontemporal_store(v, &out4[ob4 + (long)c * 25600 + r4]);
        }
    }
}

// ============ launcher ============
extern "C" void kernel_launch(void* const* d_in, const int* in_sizes, int n_in,
                              void* d_out, int out_size, void* d_ws, size_t ws_size,
                              hipStream_t stream)
{
    const float* x     = (const float*)d_in[0];
    const float* g1    = (const float*)d_in[1];
    const float* b1    = (const float*)d_in[2];
    const float* Wqkv  = (const float*)d_in[3];
    const float* bqkv  = (const float*)d_in[4];
    const float* Wproj = (const float*)d_in[5];
    const float* bproj = (const float*)d_in[6];
    const float* g2    = (const float*)d_in[7];
    const float* b2    = (const float*)d_in[8];
    const float* W1    = (const float*)d_in[9];
    const float* bm1   = (const float*)d_in[10];
    const float* W2    = (const float*)d_in[11];
    const float* bm2   = (const float*)d_in[12];
    float* out = (float*)d_out;

    char* w = (char*)d_ws;
    unsigned* wbf   = (unsigned*)w;  w += 12 * 20480;             // prepacked bf16 weights
    unsigned* kvt32 = (unsigned*)w;  w += (size_t)BN * 96 * 4;    // K|V position-major rows
    float*    xcn   = (float*)w;

    k0_pack    <<<240, 256, 0, stream>>>(Wqkv, Wproj, W1, W2, wbf);
    k1_ln_kv   <<<BN / 64, 256, 0, stream>>>(x, g1, b1, bqkv, wbf, kvt32);
    k2345      <<<BN / 64, 256, 0, stream>>>(kvt32, x, g1, b1, bqkv, wbf,
                                             bproj, g2, b2, bm1, bm2, xcn);
    k6_selfcorr<<<dim3(4, 64, 8), 256, 0, stream>>>(xcn, out);
}

// Round 5
// 395.959 us; speedup vs baseline: 1.1337x; 1.0485x over previous
//
#include <hip/hip_runtime.h>
#include <math.h>

#define NN 4096            // H*W
#define BN 32768           // B*H*W
#define CSTR 66            // Cs leading-dim pad (96 rows x 64 cols)

using short8 = __attribute__((ext_vector_type(8))) short;
using f32x4  = __attribute__((ext_vector_type(4))) float;
typedef unsigned short ushort_t;

__device__ inline unsigned f2bfu(float f) {
    unsigned u = __builtin_bit_cast(unsigned, f);
    u += 0x7FFFu + ((u >> 16) & 1u);        // RNE
    return u >> 16;
}
__device__ inline ushort_t f2bf(float f) { return (ushort_t)f2bfu(f); }
__device__ inline unsigned pack2(float a, float b) { return f2bfu(a) | (f2bfu(b) << 16); }
__device__ inline float bflo(unsigned u) { return __builtin_bit_cast(float, u << 16); }
__device__ inline float bfhi(unsigned u) { return __builtin_bit_cast(float, u & 0xFFFF0000u); }

// exact-GELU via Abramowitz-Stegun 7.1.26 erf (|err|<=1.5e-7, far below bf16 quant)
__device__ inline float gelu_f(float v) {
    float xx = v * 0.70710678118654752f;
    float a  = fabsf(xx);
    float t  = 1.0f / (1.0f + 0.3275911f * a);
    float p  = t*(0.254829592f + t*(-0.284496736f + t*(1.421413741f + t*(-1.453152027f + t*1.061405429f))));
    float erfv = 1.0f - p * __expf(-xx*xx);
    erfv = copysignf(erfv, xx);
    return 0.5f * v * (1.0f + erfv);
}

// async global->LDS copy of one prepacked 96x104-bf16 weight stage (20480 B, linear)
__device__ inline void stage_w(const unsigned* __restrict__ wbf, int stage,
                               ushort_t* dst, int wv, int lane) {
    const unsigned* src = wbf + (long)stage * 5120 + lane * 4;
    #pragma unroll
    for (int i = 0; i < 5; ++i) {
        int chunk = wv + 4 * i;               // 20 chunks x 1024 B, wave-uniform LDS base
        __builtin_amdgcn_global_load_lds(
            (const __attribute__((address_space(1))) unsigned*)(src + chunk * 256),
            (__attribute__((address_space(3))) unsigned*)(dst + chunk * 512),
            16, 0, 0);
    }
}

// A-fragment from LDS (stride 104 shorts), B from LDS weight stage
#define MFMA_GEMM6(ACC, APTR, BPTR)                                              \
    _Pragma("unroll")                                                            \
    for (int kc = 0; kc < 3; ++kc) {                                             \
        short8 a_ = *(const short8*)&(APTR)[(wv*16 + ln)*104 + kc*32 + qd*8];    \
        _Pragma("unroll")                                                        \
        for (int t = 0; t < 6; ++t) {                                            \
            short8 b_ = *(const short8*)&(BPTR)[(t*16 + ln)*104 + kc*32 + qd*8]; \
            ACC[t] = __builtin_amdgcn_mfma_f32_16x16x32_bf16(a_, b_, ACC[t], 0, 0, 0); \
        }                                                                        \
    }

// A-fragment from registers (short8 AF[3]), B from LDS weight stage
#define MFMA_GEMM6R(ACC, AF, BPTR)                                               \
    _Pragma("unroll")                                                            \
    for (int kc = 0; kc < 3; ++kc) {                                             \
        _Pragma("unroll")                                                        \
        for (int t = 0; t < 6; ++t) {                                            \
            short8 b_ = *(const short8*)&(BPTR)[(t*16 + ln)*104 + kc*32 + qd*8]; \
            ACC[t] = __builtin_amdgcn_mfma_f32_16x16x32_bf16(AF[kc], b_, ACC[t], 0, 0, 0); \
        }                                                                        \
    }

// per-row LN stats + A-fragments fully in registers.
// thread (wv,ln,qd) owns row p = wv*16+ln, channel slice {32kc+8qd+j}.
// the 4 qd-lanes of a row are lanes ln, ln+16, ln+32, ln+48 -> shfl_xor 16/32.
#define LN_FRAGS(AF, CS, G, B)                                                   \
    {                                                                            \
        const int p_ = wv*16 + ln;                                               \
        float xv_[24]; float s_ = 0.f, ss_ = 0.f;                                \
        _Pragma("unroll")                                                        \
        for (int kc = 0; kc < 3; ++kc)                                           \
            _Pragma("unroll")                                                    \
            for (int j = 0; j < 8; ++j) {                                        \
                float v_ = (CS)[(kc*32 + qd*8 + j)*CSTR + p_];                   \
                xv_[kc*8+j] = v_; s_ += v_; ss_ += v_*v_;                        \
            }                                                                    \
        s_  += __shfl_xor(s_, 16);  s_  += __shfl_xor(s_, 32);                   \
        ss_ += __shfl_xor(ss_, 16); ss_ += __shfl_xor(ss_, 32);                  \
        float m_ = s_ * (1.f/96.f);                                              \
        float rs_ = rsqrtf(ss_ * (1.f/96.f) - m_*m_ + 1e-5f);                    \
        _Pragma("unroll")                                                        \
        for (int kc = 0; kc < 3; ++kc)                                           \
            _Pragma("unroll")                                                    \
            for (int h = 0; h < 2; ++h) {                                        \
                int c0_ = kc*32 + qd*8 + h*4;                                    \
                float4 g4_ = *(const float4*)&(G)[c0_];                          \
                float4 b4_ = *(const float4*)&(B)[c0_];                          \
                (AF)[kc][h*4+0] = (short)f2bf((xv_[kc*8+h*4+0]-m_)*rs_*g4_.x + b4_.x); \
                (AF)[kc][h*4+1] = (short)f2bf((xv_[kc*8+h*4+1]-m_)*rs_*g4_.y + b4_.y); \
                (AF)[kc][h*4+2] = (short)f2bf((xv_[kc*8+h*4+2]-m_)*rs_*g4_.z + b4_.z); \
                (AF)[kc][h*4+3] = (short)f2bf((xv_[kc*8+h*4+3]-m_)*rs_*g4_.w + b4_.w); \
            }                                                                    \
    }

// ============ K0: prepack all weight tiles to bf16 LDS images ============
// stages: 0=Wq 1=Wk 2=Wv 3=Wproj 4/6/8/10=W1_kb 5/7/9/11=W2_kb
// layout: wbf dword d = stage*5120 + o*52 + qp  (row o: 48 data dwords + 4 pad)
__global__ __launch_bounds__(256) void k0_pack(
    const float* __restrict__ Wqkv, const float* __restrict__ Wproj,
    const float* __restrict__ W1, const float* __restrict__ W2,
    unsigned* __restrict__ wbf)
{
    int d = blockIdx.x * 256 + threadIdx.x;       // < 61440
    int s = d / 5120, r = d - s * 5120;
    int o = r / 52, qp = r - o * 52;
    unsigned val = 0u;
    if (o < 96 && qp < 48) {
        int q = qp * 2;
        float2 w2;
        if (s == 0)      w2 = *(const float2*)&Wqkv[(long)o * 96 + q];
        else if (s == 1) w2 = *(const float2*)&Wqkv[(long)(96 + o) * 96 + q];
        else if (s == 2) w2 = *(const float2*)&Wqkv[(long)(192 + o) * 96 + q];
        else if (s == 3) w2 = *(const float2*)&Wproj[(long)o * 96 + q];
        else if (((s - 4) & 1) == 0) { int kb = (s - 4) >> 1; w2 = *(const float2*)&W1[(long)(kb * 96 + o) * 96 + q]; }
        else                         { int kb = (s - 4) >> 1; w2 = *(const float2*)&W2[(long)o * 384 + kb * 96 + q]; }
        val = pack2(w2.x, w2.y);
    }
    wbf[d] = val;
}

// ============ K1: LN1 + K/V GEMMs -> kvt paired-channel bf16 planes ============
// kvt plane layout: plane = b*96 + kv*48 + cp (kv: 0=K,1=V), 4096 u32/plane
__global__ __launch_bounds__(256, 2) void k1_ln_kv(
    const float* __restrict__ x, const float* __restrict__ g1, const float* __restrict__ b1,
    const float* __restrict__ bqkv, const unsigned* __restrict__ wbf,
    unsigned* __restrict__ kvt32)
{
    __shared__ __align__(16) float    Cs[96 * CSTR];
    __shared__ __align__(16) ushort_t Bs[2][10240];
    const int tid = threadIdx.x;
    const int bid = blockIdx.x;
    const int wg  = ((bid & 7) << 6) | (bid >> 3);   // XCD-chunked: image b == XCD
    const long bn0 = (long)wg << 6;
    const int b  = (int)(bn0 >> 12);
    const int n0 = (int)(bn0 & 4095);
    const int lane = tid & 63, wv = tid >> 6;
    const int ln = lane & 15, qd = lane >> 4;

    stage_w(wbf, 1, &Bs[0][0], wv, lane);    // Wk
    stage_w(wbf, 2, &Bs[1][0], wv, lane);    // Wv
    for (int i = 0; i < 6; ++i) {
        int idx = i * 256 + tid;             // 1536 float4
        int c = idx >> 4, p4 = idx & 15;
        float4 v = *(const float4*)&x[((long)(b * 96 + c) << 12) + n0 + p4 * 4];
        float* dst = &Cs[c * CSTR + p4 * 4];
        dst[0] = v.x; dst[1] = v.y; dst[2] = v.z; dst[3] = v.w;
    }
    __syncthreads();                                   // S1: x, Wk, Wv landed
    // ---- LN1 -> A-fragments in registers ----
    short8 af[3];
    LN_FRAGS(af, Cs, g1, b1);
    // ---- K GEMM (regs only; Cs untouched) ----
    f32x4 acck[6];
    #pragma unroll
    for (int t = 0; t < 6; ++t) acck[t] = (f32x4){0.f,0.f,0.f,0.f};
    MFMA_GEMM6R(acck, af, Bs[0]);
    __syncthreads();                                   // S2: all x reads of Cs done
    #pragma unroll
    for (int t = 0; t < 6; ++t)
        #pragma unroll
        for (int r = 0; r < 4; ++r)
            Cs[(t*16 + ln)*CSTR + (wv*16 + qd*4 + r)] = acck[t][r];
    __syncthreads();                                   // S3: Cs = K
    // ---- pack K -> kvt planes; V GEMM (regs) overlaps ----
    f32x4 accv[6];
    #pragma unroll
    for (int t = 0; t < 6; ++t) accv[t] = (f32x4){0.f,0.f,0.f,0.f};
    for (int i = 0; i < 12; ++i) {
        int idx = i * 256 + tid;
        int cp = idx / 64, p = idx % 64;
        int c = 2 * cp;
        kvt32[((long)(b*96 + cp) << 12) + n0 + p] =
            pack2(Cs[c*CSTR + p] + bqkv[96 + c], Cs[(c+1)*CSTR + p] + bqkv[96 + c + 1]);
    }
    MFMA_GEMM6R(accv, af, Bs[1]);
    __syncthreads();                                   // S4: K-pack reads of Cs done
    #pragma unroll
    for (int t = 0; t < 6; ++t)
        #pragma unroll
        for (int r = 0; r < 4; ++r)
            Cs[(t*16 + ln)*CSTR + (wv*16 + qd*4 + r)] = accv[t][r];
    __syncthreads();                                   // S5: Cs = V
    for (int i = 0; i < 12; ++i) {
        int idx = i * 256 + tid;
        int cp = idx / 64, p = idx % 64;
        int c = 2 * cp;
        kvt32[((long)(b*96 + 48 + cp) << 12) + n0 + p] =
            pack2(Cs[c*CSTR + p] + bqkv[192 + c], Cs[(c+1)*CSTR + p] + bqkv[192 + c + 1]);
    }
}

// ============ K2345: Q-GEMM + attention + proj + LN2 + MLP + ReLU + L2norm ============
__global__ __launch_bounds__(256, 2) void k2345(
    const unsigned* __restrict__ kvt32, const float* __restrict__ x,
    const float* __restrict__ g1, const float* __restrict__ b1,
    const float* __restrict__ bqkv, const unsigned* __restrict__ wbf,
    const float* __restrict__ bproj,
    const float* __restrict__ g2, const float* __restrict__ b2,
    const float* __restrict__ bm1, const float* __restrict__ bm2,
    float* __restrict__ xcn)
{
    __shared__ __align__(16) float    Cs[96 * CSTR];   // x / xh'; bytes reused as Hs in MLP
    __shared__ __align__(16) ushort_t As[64 * 104];    // Q -> attn-out
    __shared__ __align__(16) ushort_t Bs[2][10240];    // double-buffered weight stages
    __shared__ float lnr[64];
    ushort_t* Hs = (ushort_t*)Cs;                      // MLP hidden frags (Cs dead then)
    const int tid = threadIdx.x;
    const int bid = blockIdx.x;
    const int wg  = ((bid & 7) << 6) | (bid >> 3);     // XCD-chunked swizzle
    const long bn0 = (long)wg << 6;
    const int b  = (int)(bn0 >> 12);
    const int n0 = (int)(bn0 & 4095);
    const int h0 = n0 >> 6;
    const int lane = tid & 63, wv = tid >> 6;
    const int ln = lane & 15, qd = lane >> 4;

    stage_w(wbf, 0, &Bs[0][0], wv, lane);    // Wq
    stage_w(wbf, 3, &Bs[1][0], wv, lane);    // Wproj
    for (int i = 0; i < 6; ++i) {
        int idx = i * 256 + tid;                       // 1536 float4
        int c = idx >> 4, p4 = idx & 15;
        float4 v = *(const float4*)&x[((long)(b * 96 + c) << 12) + n0 + p4 * 4];
        float* dst = &Cs[c * CSTR + p4 * 4];
        dst[0] = v.x; dst[1] = v.y; dst[2] = v.z; dst[3] = v.w;
    }
    __syncthreads();                                   // S1: x + Wq + Wproj ready
    // ---- LN1 -> A-fragments in registers; Q MFMA -> As (A-frag layout) ----
    {
        short8 af[3];
        LN_FRAGS(af, Cs, g1, b1);
        f32x4 acc[6];
        #pragma unroll
        for (int t = 0; t < 6; ++t) acc[t] = (f32x4){0.f,0.f,0.f,0.f};
        MFMA_GEMM6R(acc, af, Bs[0]);
        #pragma unroll
        for (int t = 0; t < 6; ++t) {
            float bias = bqkv[t*16 + ln];
            #pragma unroll
            for (int r = 0; r < 4; ++r)
                As[(wv*16 + qd*4 + r)*104 + t*16 + ln] = f2bf(acc[t][r] + bias);
        }
    }
    __syncthreads();                                   // S2: As = Q
    stage_w(wbf, 4, &Bs[0][0], wv, lane);              // W1_0 under attention
    // ---- attention: q from As (LDS), K/V plane-major (wave-coalesced 4B loads) ----
    for (int it = 0; it < 2; ++it) {
        int item = it * 256 + tid;          // 64 pos x 6 (dil,head) = 384 items
        if (item < 384) {
            int p = item & 63;
            int r = item >> 6;
            int head = r & 1, di = r >> 1;
            int dil = di + 1;
            int cp0 = di*16 + head*8;       // dword-channel offset
            const unsigned* K = kvt32 + ((long)(b*96 +      cp0) << 12);
            const unsigned* V = kvt32 + ((long)(b*96 + 48 + cp0) << 12);
            int w = p;

            float q[16];
            #pragma unroll
            for (int j = 0; j < 8; ++j) {
                unsigned u = *(const unsigned*)&As[p * 104 + 2*(cp0 + j)];
                q[2*j] = bflo(u); q[2*j+1] = bfhi(u);
            }
            float logits[9];
            #pragma unroll
            for (int ki = 0; ki < 3; ++ki)
                #pragma unroll
                for (int kj = 0; kj < 3; ++kj) {
                    int hh = h0 + (ki-1)*dil, ww = w + (kj-1)*dil;
                    float l = 0.f;
                    if ((unsigned)hh < 64u && (unsigned)ww < 64u) {
                        int nn = (hh << 6) + ww;
                        #pragma unroll
                        for (int j = 0; j < 8; ++j) {
                            unsigned u = K[((long)j << 12) + nn];
                            l += q[2*j] * bflo(u) + q[2*j+1] * bfhi(u);
                        }
                    }
                    logits[ki*3 + kj] = l * 0.25f;
                }
            float m = logits[0];
            #pragma unroll
            for (int k = 1; k < 9; ++k) m = fmaxf(m, logits[k]);
            float e[9], s = 0.f;
            #pragma unroll
            for (int k = 0; k < 9; ++k) { e[k] = __expf(logits[k] - m); s += e[k]; }
            float inv = 1.f / s;
            float o[16];
            #pragma unroll
            for (int d = 0; d < 16; ++d) o[d] = 0.f;
            #pragma unroll
            for (int ki = 0; ki < 3; ++ki)
                #pragma unroll
                for (int kj = 0; kj < 3; ++kj) {
                    int hh = h0 + (ki-1)*dil, ww = w + (kj-1)*dil;
                    if ((unsigned)hh < 64u && (unsigned)ww < 64u) {
                        int nn = (hh << 6) + ww;
                        float wgt = e[ki*3 + kj] * inv;
                        #pragma unroll
                        for (int j = 0; j < 8; ++j) {
                            unsigned u = V[((long)j << 12) + nn];
                            o[2*j]   += wgt * bflo(u);
                            o[2*j+1] += wgt * bfhi(u);
                        }
                    }
                }
            #pragma unroll
            for (int j = 0; j < 8; ++j)
                *(unsigned*)&As[p * 104 + 2*(cp0 + j)] = pack2(o[2*j], o[2*j+1]);
        }
    }
    __syncthreads();                                   // S3: As = attn out; W1_0 landed
    // ---- proj MFMA; residual in regs (x read from Cs) ----
    float resid[24];
    {
        f32x4 acc[6];
        #pragma unroll
        for (int t = 0; t < 6; ++t) acc[t] = (f32x4){0.f,0.f,0.f,0.f};
        MFMA_GEMM6(acc, As, Bs[1]);
        #pragma unroll
        for (int t = 0; t < 6; ++t) {
            int oc = t*16 + ln;
            float bias = bproj[oc];
            #pragma unroll
            for (int r = 0; r < 4; ++r) {
                int p = wv*16 + qd*4 + r;
                float v = acc[t][r] + bias + Cs[oc*CSTR + p];
                resid[t*4 + r] = v;
                Cs[oc*CSTR + p] = v;                   // xh' -> Cs
            }
        }
    }
    __syncthreads();                                   // S4: Cs = xh'
    stage_w(wbf, 5, &Bs[1][0], wv, lane);              // W2_0 under LN2
    // ---- LN2 -> z fragments in registers (reused across all 4 kb) ----
    short8 zf[3];
    LN_FRAGS(zf, Cs, g2, b2);
    __syncthreads();                                   // S5: all Cs reads done -> Hs writable
    // ---- MLP: W1_{kb+1} hides under GEMM2_kb, W2_{kb+1} under GEMM1_{kb+1} ----
    f32x4 acc2[6];
    #pragma unroll
    for (int t = 0; t < 6; ++t) acc2[t] = (f32x4){0.f,0.f,0.f,0.f};
    for (int kb = 0; kb < 4; ++kb) {
        f32x4 acch[6];
        #pragma unroll
        for (int t = 0; t < 6; ++t) acch[t] = (f32x4){0.f,0.f,0.f,0.f};
        MFMA_GEMM6R(acch, zf, Bs[0]);                  // GEMM1: W1_kb
        #pragma unroll
        for (int t = 0; t < 6; ++t) {
            float bias = bm1[kb*96 + t*16 + ln];
            #pragma unroll
            for (int r = 0; r < 4; ++r)
                Hs[(wv*16 + qd*4 + r)*104 + t*16 + ln] = f2bf(gelu_f(acch[t][r] + bias));
        }
        __syncthreads();                               // B1: Hs ready, Bs0 free
        if (kb < 3) stage_w(wbf, 6 + 2*kb, &Bs[0][0], wv, lane);   // W1_{kb+1}
        MFMA_GEMM6(acc2, Hs, Bs[1]);                   // GEMM2: W2_kb
        __syncthreads();                               // B2: Bs1 free; W1_{kb+1} landed
        if (kb < 3) stage_w(wbf, 7 + 2*kb, &Bs[1][0], wv, lane);   // W2_{kb+1}
    }
    // ---- final residual + relu -> Cs ----
    #pragma unroll
    for (int t = 0; t < 6; ++t) {
        int oc = t*16 + ln;
        float bias = bm2[oc];
        #pragma unroll
        for (int r = 0; r < 4; ++r) {
            int p = wv*16 + qd*4 + r;
            float v = acc2[t][r] + bias + resid[t*4 + r];
            Cs[oc*CSTR + p] = fmaxf(v, 0.f);
        }
    }
    __syncthreads();                                   // S6
    // ---- L2 norm over channels ----
    {
        int p = tid >> 2, part = tid & 3, c0 = part * 24;
        float ss = 0.f;
        for (int c = c0; c < c0 + 24; ++c) { float v = Cs[c*CSTR + p]; ss += v*v; }
        ss += __shfl_xor(ss, 1); ss += __shfl_xor(ss, 2);
        if (part == 0) lnr[p] = 1.f / fmaxf(sqrtf(ss), 1e-12f);
    }
    __syncthreads();                                   // S7
    for (int i = 0; i < 12; ++i) {
        int idx = i * 256 + tid;
        int p = idx / 48, cp = idx % 48;
        float inv = lnr[p];
        float2 v = make_float2(Cs[(2*cp)*CSTR + p] * inv, Cs[(2*cp+1)*CSTR + p] * inv);
        *(float2*)&xcn[(bn0 + p) * 96 + 2*cp] = v;
    }
}

// ============ K6: 5x5 self-correlation (vectorized halo stage, nontemporal stores) ============
__global__ __launch_bounds__(256) void k6_selfcorr(
    const float* __restrict__ xcn, float* __restrict__ out)
{
    __shared__ float xt[5 * 20 * 97];
    const int tid = threadIdx.x;
    const int wc = blockIdx.x;
    const int h  = blockIdx.y;
    const int b  = blockIdx.z;
    const int w0 = wc * 16;

    const f32x4* xcn4 = (const f32x4*)xcn;
    for (int i = 0; i < 10; ++i) {
        int idx = i * 256 + tid;                       // 2400 float4 slots
        if (idx < 2400) {
            int r = idx / 480;
            int rem = idx - r * 480;
            int wi = rem / 24, c4 = rem - wi * 24;
            int hh = h + r - 2, ww = w0 + wi - 2;
            f32x4 v = (f32x4){0.f, 0.f, 0.f, 0.f};
            if ((unsigned)hh < 64u && (unsigned)ww < 64u)
                v = xcn4[(((long)b << 12) + (hh << 6) + ww) * 24 + c4];
            float* dst = &xt[(r * 20 + wi) * 97 + c4 * 4];
            dst[0] = v[0]; dst[1] = v[1]; dst[2] = v[2]; dst[3] = v[3];
        }
    }
    __syncthreads();
    f32x4* out4 = (f32x4*)out;
    const long ob4 = (long)b * 2457600 + (long)h * 400 + wc * 100;
    for (int i = 0; i < 38; ++i) {
        int idx = i * 256 + tid;             // 9600 float4 slots
        if (idx < 9600) {
            int c = idx / 100;
            int r4 = idx - c * 100;
            f32x4 v;
            #pragma unroll
            for (int j = 0; j < 4; ++j) {
                int r = r4 * 4 + j;
                int lw = r / 25, k = r - lw * 25;
                int ki = k / 5, kj = k - ki * 5;
                float center = xt[(42 + lw) * 97 + c];
                float neigh  = xt[(ki * 20 + lw + kj) * 97 + c];
                v[j] = center * neigh;
            }
            __builtin_nontemporal_store(v, &out4[ob4 + (long)c * 25600 + r4]);
        }
    }
}

// ============ launcher ============
extern "C" void kernel_launch(void* const* d_in, const int* in_sizes, int n_in,
                              void* d_out, int out_size, void* d_ws, size_t ws_size,
                              hipStream_t stream)
{
    const float* x     = (const float*)d_in[0];
    const float* g1    = (const float*)d_in[1];
    const float* b1    = (const float*)d_in[2];
    const float* Wqkv  = (const float*)d_in[3];
    const float* bqkv  = (const float*)d_in[4];
    const float* Wproj = (const float*)d_in[5];
    const float* bproj = (const float*)d_in[6];
    const float* g2    = (const float*)d_in[7];
    const float* b2    = (const float*)d_in[8];
    const float* W1    = (const float*)d_in[9];
    const float* bm1   = (const float*)d_in[10];
    const float* W2    = (const float*)d_in[11];
    const float* bm2   = (const float*)d_in[12];
    float* out = (float*)d_out;

    char* w = (char*)d_ws;
    unsigned* wbf   = (unsigned*)w;  w += 12 * 20480;             // prepacked bf16 weights
    unsigned* kvt32 = (unsigned*)w;  w += (size_t)BN * 192 * 2;   // K,V bf16 plane pairs
    float*    xcn   = (float*)w;

    k0_pack    <<<240, 256, 0, stream>>>(Wqkv, Wproj, W1, W2, wbf);
    k1_ln_kv   <<<BN / 64, 256, 0, stream>>>(x, g1, b1, bqkv, wbf, kvt32);
    k2345      <<<BN / 64, 256, 0, stream>>>(kvt32, x, g1, b1, bqkv, wbf,
                                             bproj, g2, b2, bm1, bm2, xcn);
    k6_selfcorr<<<dim3(4, 64, 8), 256, 0, stream>>>(xcn, out);
}